// Round 5
// baseline (996.332 us; speedup 1.0000x reference)
//
#include <hip/hip_runtime.h>

#define N_NODES 20000
#define N_EDGES 100000
#define CIN     64
#define A_DIM   32
#define CCH     256
#define NBOX    128
#define FD      1024
#define HID     1024
#define OUT_STRIDE 2048

typedef __attribute__((ext_vector_type(8))) short          short8;
typedef __attribute__((ext_vector_type(8))) unsigned short ushort8;
typedef __attribute__((ext_vector_type(4))) unsigned short ushort4v;
typedef __attribute__((ext_vector_type(4))) float          floatx4;

__device__ __forceinline__ unsigned short f2bf(float f) {
    unsigned int u = __float_as_uint(f);
    u += 0x7fff + ((u >> 16) & 1);
    return (unsigned short)(u >> 16);
}
__device__ __forceinline__ float bf2f(unsigned short h) {
    return __uint_as_float(((unsigned int)h) << 16);
}

// async global->LDS, 16B per lane; LDS dest is wave-uniform base + lane*16
__device__ __forceinline__ void glds16(const unsigned short* g, unsigned short* l) {
    __builtin_amdgcn_global_load_lds(
        (const __attribute__((address_space(1))) unsigned int*)g,
        (__attribute__((address_space(3))) unsigned int*)l,
        16, 0, 0);
}

// ---------------------------------------------------------------------------
// Dense MFMA GEMM, 128x128 tile, BK=32, global_load_lds staging, 2-phase
// double-buffered pipeline: STAGE(t+1) issues before compute(t); ONE barrier
// per K-step (drains the prefetch loads while compute covers the latency).
// A = [seg0 (C0 cols) | seg1] rows, both bf16; optional row remap on seg0 via
// ridx0. B = bf16 Wt[n][k]. Epilogue: (+bias, relu opt) -> fp32 out and/or
// bf16 out; rmode==2 writes the dense 4-layer R buffer:
//   idx = layer(gc>>8)*E*256 + row*256 + (gc&255).
// XCD-aware bijective blockIdx swizzle for row-panel L2 locality.
// ---------------------------------------------------------------------------
__global__ __launch_bounds__(256) void mfma_dense(
    const unsigned short* __restrict__ src0b, int s0, int o0, int C0,
    const int* __restrict__ ridx0,
    const unsigned short* __restrict__ src1b, int s1, int o1,
    const unsigned short* __restrict__ Wt, const float* __restrict__ bias,
    int do_relu,
    float* __restrict__ outf, int sof, int oof,
    unsigned short* __restrict__ outb, int sob, int oob, int rmode,
    int M, int K, int nbc)
{
    __shared__ __align__(16) unsigned short As[2][128 * 32];
    __shared__ __align__(16) unsigned short Bs[2][128 * 32];

    const int tid  = threadIdx.x;

    // bijective XCD swizzle (works for any gridDim)
    const int nwg  = gridDim.x;
    const int q8   = nwg >> 3, r8 = nwg & 7;
    const int xcd  = blockIdx.x & 7, boff = blockIdx.x >> 3;
    const int bid  = (xcd < r8 ? xcd * (q8 + 1)
                               : r8 * (q8 + 1) + (xcd - r8) * q8) + boff;

    const int rb   = bid / nbc, cb = bid % nbc;
    const int r0   = rb * 128, c0 = cb * 128;
    const int wave = tid >> 6, lane = tid & 63;
    const int quad = lane >> 4, l16 = lane & 15;
    const int wm   = (wave & 1) * 64, wn = (wave >> 1) * 64;

    // staging slot geometry: slot g = i*256 + tid covers LDS bytes [g*16, g*16+16)
    // row = g>>2 (64B rows), k-chunk = (g&3)*8 bf16
    int arow[2], grow[2], brow[2], kch[2];
    #pragma unroll
    for (int i = 0; i < 2; ++i) {
        const int g  = i * 256 + tid;
        const int rr = g >> 2;
        kch[i] = (g & 3) << 3;
        int gr2 = r0 + rr;
        if (gr2 >= M) gr2 = M - 1;
        grow[i] = gr2;
        arow[i] = ridx0 ? ridx0[gr2] : gr2;
        brow[i] = c0 + rr;
    }

    auto STAGE = [&](int buf, int k0) {
        unsigned short* AsW = &As[buf][wave * 512];
        unsigned short* BsW = &Bs[buf][wave * 512];
        #pragma unroll
        for (int i = 0; i < 2; ++i) {
            const int kk = k0 + kch[i];
            const unsigned short* ga = (kk < C0)
                ? src0b + (long)arow[i] * s0 + o0 + kk
                : src1b + (long)grow[i] * s1 + o1 + (kk - C0);
            glds16(ga, AsW + i * 2048);
            glds16(Wt + (long)brow[i] * K + k0 + kch[i], BsW + i * 2048);
        }
    };

    floatx4 acc[4][4];
    #pragma unroll
    for (int i = 0; i < 4; ++i)
        #pragma unroll
        for (int j = 0; j < 4; ++j) acc[i][j] = (floatx4){0.f, 0.f, 0.f, 0.f};

    const int nt = K >> 5;
    STAGE(0, 0);
    __syncthreads();
    int cur = 0;
    for (int t = 0; t < nt; ++t) {
        if (t + 1 < nt) STAGE(cur ^ 1, (t + 1) << 5);

        short8 af[4], bfr[4];
        #pragma unroll
        for (int mt = 0; mt < 4; ++mt)
            af[mt] = *(const short8*)(&As[cur][(wm + mt * 16 + l16) * 32 + quad * 8]);
        #pragma unroll
        for (int nt2 = 0; nt2 < 4; ++nt2)
            bfr[nt2] = *(const short8*)(&Bs[cur][(wn + nt2 * 16 + l16) * 32 + quad * 8]);
        #pragma unroll
        for (int mt = 0; mt < 4; ++mt)
            #pragma unroll
            for (int nt2 = 0; nt2 < 4; ++nt2)
                acc[mt][nt2] = __builtin_amdgcn_mfma_f32_16x16x32_bf16(
                    af[mt], bfr[nt2], acc[mt][nt2], 0, 0, 0);
        __syncthreads();   // drains prefetch vmcnt + frees buf[cur] for overwrite
        cur ^= 1;
    }

    #pragma unroll
    for (int nt2 = 0; nt2 < 4; ++nt2) {
        const int gc = c0 + wn + nt2 * 16 + l16;
        const float bv = bias ? bias[gc] : 0.f;
        #pragma unroll
        for (int mt = 0; mt < 4; ++mt) {
            #pragma unroll
            for (int reg = 0; reg < 4; ++reg) {
                const int grr = r0 + wm + mt * 16 + quad * 4 + reg;
                if (grr < M) {
                    float v = acc[mt][nt2][reg] + bv;
                    if (do_relu) v = fmaxf(v, 0.f);
                    if (outf) outf[(long)grr * sof + oof + gc] = v;
                    if (outb) {
                        long idx = (rmode == 2)
                            ? ((long)(gc >> 8) * ((long)N_EDGES * 256)
                               + (long)grr * 256 + (gc & 255))
                            : ((long)grr * sob + oob + gc);
                        outb[idx] = f2bf(v);
                    }
                }
            }
        }
    }
}

// ---------------------------------------------------------------------------
// fp32 -> bf16 bulk convert (n multiple of 4)
// ---------------------------------------------------------------------------
__global__ void f32_to_bf16(const float* __restrict__ in,
                            unsigned short* __restrict__ out, int n4) {
    int i = blockIdx.x * blockDim.x + threadIdx.x;
    if (i < n4) {
        float4 v = ((const float4*)in)[i];
        ushort4v h = (ushort4v){f2bf(v.x), f2bf(v.y), f2bf(v.z), f2bf(v.w)};
        ((ushort4v*)out)[i] = h;
    }
}

// ---------------------------------------------------------------------------
// Aggregation: one wave per dst node. f_out[d] = sum_e relu(P[d]+Q[src]+R[e]+b)
// * ew[e]  (+ residual). Edges CSR-sorted by dst -> no atomics. One-deep
// software prefetch; R read is DENSE sequential (Rb[s*256+c]).
// Writes fp32 into out (final feats_cat) AND bf16 into nfbf (GEMM A input).
// ---------------------------------------------------------------------------
__global__ __launch_bounds__(256) void agg_kernel(
    const unsigned short* __restrict__ pq,   // [N,512] bf16: [P | Q]
    const int* __restrict__ rowptr,
    const int* __restrict__ ssrc,
    const float* __restrict__ sew,
    const unsigned short* __restrict__ Rb,   // dense [E,256] bf16 (this layer)
    const float* __restrict__ resid,         // residual source (out) if rofs>=0
    const float* __restrict__ bias,
    float* __restrict__ out, int fofs, int rofs,
    unsigned short* __restrict__ nfbf, int nofs)
{
    const int wid  = (blockIdx.x * blockDim.x + threadIdx.x) >> 6;
    const int lane = threadIdx.x & 63;
    if (wid >= N_NODES) return;
    const int c = lane * 4;

    const ushort4v p4 = *(const ushort4v*)(pq + (long)wid * 512 + c);
    const float4 bb = *(const float4*)(bias + c);
    float pb[4] = {bf2f(p4[0]) + bb.x, bf2f(p4[1]) + bb.y,
                   bf2f(p4[2]) + bb.z, bf2f(p4[3]) + bb.w};
    float acc[4] = {0.f, 0.f, 0.f, 0.f};

    int s = rowptr[wid];
    const int sEnd = rowptr[wid + 1];

    ushort4v q4n, r4n;
    float wn_ = 0.f;
    if (s < sEnd) {
        const int srcn = ssrc[s];
        wn_ = sew[s];
        q4n = *(const ushort4v*)(pq + (long)srcn * 512 + 256 + c);
        r4n = *(const ushort4v*)(Rb + (long)s * 256 + c);
    }
    while (s < sEnd) {
        const ushort4v q4 = q4n, r4 = r4n;
        const float wgt = wn_;
        ++s;
        if (s < sEnd) {
            const int srcn = ssrc[s];
            wn_ = sew[s];
            q4n = *(const ushort4v*)(pq + (long)srcn * 512 + 256 + c);
            r4n = *(const ushort4v*)(Rb + (long)s * 256 + c);
        }
        #pragma unroll
        for (int j = 0; j < 4; ++j)
            acc[j] += fmaxf(pb[j] + bf2f(q4[j]) + bf2f(r4[j]), 0.f) * wgt;
    }
    if (rofs >= 0) {
        const float4 f4 = *(const float4*)(resid + (long)wid * OUT_STRIDE + rofs + c);
        acc[0] += f4.x; acc[1] += f4.y; acc[2] += f4.z; acc[3] += f4.w;
    }
    float4 o; o.x = acc[0]; o.y = acc[1]; o.z = acc[2]; o.w = acc[3];
    *(float4*)(out + (long)wid * OUT_STRIDE + fofs + c) = o;
    ushort4v hb = (ushort4v){f2bf(acc[0]), f2bf(acc[1]), f2bf(acc[2]), f2bf(acc[3])};
    *(ushort4v*)(nfbf + (long)wid * FD + nofs + c) = hb;
}

// ---------------------------------------------------------------------------
// Weight prep
// ---------------------------------------------------------------------------
// Wpq[n][k]: n<256 -> W0-W1 column n; n>=256 -> W1 column n-256.  W is [2F+32,256].
__global__ void wpq_prep(const float* __restrict__ W, unsigned short* __restrict__ Wpq, int F) {
    int i = blockIdx.x * blockDim.x + threadIdx.x;
    if (i < 512 * F) {
        int nn = i / F, k = i % F;
        float v = (nn < 256) ? (W[k * 256 + nn] - W[(F + k) * 256 + nn])
                             : W[(F + k) * 256 + (nn - 256)];
        Wpq[(long)nn * F + k] = f2bf(v);
    }
}

// Tiled (LDS, coalesced both sides) version of wpq_prep for the 3 ResBlocks.
// Output [512][256] per slab; grid.x = 16*8 = 128, grid.y = slab.
__global__ __launch_bounds__(256) void wpq_prep3_tiled(
    const float* __restrict__ W, unsigned short* __restrict__ Wpq)
{
    __shared__ float tile[32][33];
    const float* Wi = W + (long)blockIdx.y * 544 * 256;
    unsigned short* Wo = Wpq + (long)blockIdx.y * 512 * 256;
    const int nbx = 16;                       // 512/32 n-tiles
    const int n0 = (blockIdx.x % nbx) << 5;
    const int k0 = (blockIdx.x / nbx) << 5;
    const int tx = threadIdx.x & 31, ty = threadIdx.x >> 5;
    #pragma unroll
    for (int r = 0; r < 4; ++r) {
        const int k = k0 + ty + r * 8;
        float v;
        if (n0 < 256)
            v = Wi[(long)k * 256 + n0 + tx] - Wi[(long)(256 + k) * 256 + n0 + tx];
        else
            v = Wi[(long)(256 + k) * 256 + (n0 - 256) + tx];
        tile[ty + r * 8][tx] = v;
    }
    __syncthreads();
    #pragma unroll
    for (int r = 0; r < 4; ++r)
        Wo[(long)(n0 + ty + r * 8) * 256 + k0 + tx] = f2bf(tile[tx][ty + r * 8]);
}

// Generic LDS-tiled transpose+convert: out[n][k] = bf16(in[k][n]).
// K,N multiples of 32; grid.x = (K/32)*(N/32), grid.y = batch.
__global__ __launch_bounds__(256) void transpose_tiled(
    const float* __restrict__ in, unsigned short* __restrict__ out,
    int K, int N, long istride, long ostride)
{
    __shared__ float tile[32][33];
    const float* inp = in + (long)blockIdx.y * istride;
    unsigned short* outp = out + (long)blockIdx.y * ostride;
    const int nbx = N >> 5;
    const int n0 = (blockIdx.x % nbx) << 5;
    const int k0 = (blockIdx.x / nbx) << 5;
    const int tx = threadIdx.x & 31, ty = threadIdx.x >> 5;
    #pragma unroll
    for (int r = 0; r < 4; ++r)
        tile[ty + r * 8][tx] = inp[(long)(k0 + ty + r * 8) * N + n0 + tx];
    __syncthreads();
    #pragma unroll
    for (int r = 0; r < 4; ++r)
        outp[(long)(n0 + ty + r * 8) * K + k0 + tx] = f2bf(tile[tx][ty + r * 8]);
}

// 4 edge-weight transposes (32x256 -> 256x32) in one launch; blockIdx.y=0 is
// the head slice (from W_msg0), 1..3 are the ResBlock slices (from W_msg).
// Concatenated output wtr is [1024][32] (layer-major) for the merged R GEMM.
__global__ void wtr_prep(const float* __restrict__ W_msg0,
                         const float* __restrict__ W_msg,
                         unsigned short* __restrict__ wtr) {
    const int j = blockIdx.y;
    const float* Wi = (j == 0) ? (W_msg0 + 2 * CIN * 256)
                               : (W_msg + (long)(j - 1) * 544 * 256 + 2 * CCH * 256);
    unsigned short* Wo = wtr + (long)j * 256 * 32;
    int i = blockIdx.x * blockDim.x + threadIdx.x;
    if (i < 32 * 256) {
        int k = i / 256, n = i % 256;
        Wo[(long)n * 32 + k] = f2bf(Wi[i]);
    }
}

// ---------------------------------------------------------------------------
// CSR build
// ---------------------------------------------------------------------------
__global__ void zero_int(int* p, int n) {
    int i = blockIdx.x * blockDim.x + threadIdx.x;
    if (i < n) p[i] = 0;
}
__global__ void hist_kernel(const int* __restrict__ keys, int n, int* __restrict__ cnt) {
    int i = blockIdx.x * blockDim.x + threadIdx.x;
    if (i < n) atomicAdd(&cnt[keys[i]], 1);
}
__global__ __launch_bounds__(1024) void scan_kernel(const int* __restrict__ cnt,
                                                    int* __restrict__ rowptr,
                                                    int* __restrict__ ofs, int n) {
    __shared__ int part[1024];
    const int tid = threadIdx.x;
    const int chunk = (n + 1023) >> 10;
    int s = 0;
    for (int j = 0; j < chunk; ++j) {
        int i = tid * chunk + j;
        if (i < n) s += cnt[i];
    }
    part[tid] = s; __syncthreads();
    for (int d = 1; d < 1024; d <<= 1) {
        int v = (tid >= d) ? part[tid - d] : 0;
        __syncthreads();
        part[tid] += v;
        __syncthreads();
    }
    int run = (tid > 0) ? part[tid - 1] : 0;
    for (int j = 0; j < chunk; ++j) {
        int i = tid * chunk + j;
        if (i < n) { rowptr[i] = run; ofs[i] = run; run += cnt[i]; }
    }
    if (tid == 1023) rowptr[n] = part[1023];
}
__global__ void scatter_edges(const int* __restrict__ src, const int* __restrict__ dst,
                              const float* __restrict__ ew, int* __restrict__ ofs,
                              int* __restrict__ ssrc, float* __restrict__ sew,
                              int* __restrict__ seid) {
    int e = blockIdx.x * blockDim.x + threadIdx.x;
    if (e < N_EDGES) {
        int pos = atomicAdd(&ofs[dst[e]], 1);
        ssrc[pos] = src[e];
        sew[pos]  = ew[e];
        seid[pos] = e;
    }
}
__global__ void scatter_box(const int* __restrict__ bbox, int* __restrict__ ofs,
                            int* __restrict__ snode) {
    int i = blockIdx.x * blockDim.x + threadIdx.x;
    if (i < N_NODES) {
        int pos = atomicAdd(&ofs[bbox[i]], 1);
        snode[pos] = i;
    }
}

// ---------------------------------------------------------------------------
// Box mean via CSR (no atomics). Emits fp32 into out_super and bf16 fsmean.
// ---------------------------------------------------------------------------
__global__ __launch_bounds__(256) void box_mean_csr(
    const unsigned short* __restrict__ fsbf, const int* __restrict__ bptr,
    const int* __restrict__ snode, float* __restrict__ out_super,
    unsigned short* __restrict__ fsmeanb)
{
    const int b = blockIdx.x >> 2;
    const int c = ((blockIdx.x & 3) << 8) + threadIdx.x;
    const int s0 = bptr[b], s1 = bptr[b + 1];
    float sum = 0.f;
    for (int s = s0; s < s1; ++s)
        sum += bf2f(fsbf[(long)snode[s] * FD + c]);
    const float mean = sum / fmaxf((float)(s1 - s0), 1.f);
    out_super[(long)b * OUT_STRIDE + HID + c] = mean;
    fsmeanb[(long)b * FD + c] = f2bf(mean);
}

// ---------------------------------------------------------------------------
extern "C" void kernel_launch(void* const* d_in, const int* in_sizes, int n_in,
                              void* d_out, int out_size, void* d_ws, size_t ws_size,
                              hipStream_t stream) {
    const float* x      = (const float*)d_in[0];
    const int*   edges  = (const int*)d_in[1];
    const float* ew     = (const float*)d_in[2];
    const float* ea     = (const float*)d_in[3];
    const int*   bbox   = (const int*)d_in[4];
    const float* W_msg0 = (const float*)d_in[6];
    const float* b_msg0 = (const float*)d_in[7];
    const float* W_sup0 = (const float*)d_in[8];
    const float* b_sup0 = (const float*)d_in[9];
    const float* W_msg  = (const float*)d_in[10];
    const float* b_msg  = (const float*)d_in[11];
    const float* W_sup  = (const float*)d_in[12];
    const float* b_sup  = (const float*)d_in[13];
    const float* W_fuse = (const float*)d_in[14];
    const float* b_fuse = (const float*)d_in[15];
    const float* W_fsup = (const float*)d_in[16];
    const float* b_fsup = (const float*)d_in[17];

    float* out       = (float*)d_out;
    float* out_super = out + (long)N_NODES * OUT_STRIDE;

    // ---- workspace layout ----
    char* w = (char*)d_ws;
    auto alloc = [&](size_t bytes) { char* p = w; w += (bytes + 63) & ~63ULL; return p; };
    unsigned short* fsbf    = (unsigned short*)alloc((size_t)N_NODES * FD * 2);
    unsigned short* nfbf    = (unsigned short*)alloc((size_t)N_NODES * FD * 2);
    unsigned short* pq      = (unsigned short*)alloc((size_t)N_NODES * 512 * 2);
    unsigned short* xb      = (unsigned short*)alloc((size_t)N_NODES * CIN * 2);
    unsigned short* eab     = (unsigned short*)alloc((size_t)N_EDGES * A_DIM * 2);
    unsigned short* Rb4     = (unsigned short*)alloc((size_t)N_EDGES * 1024 * 2);
    unsigned short* wpq0    = (unsigned short*)alloc((size_t)512 * CIN * 2);
    unsigned short* wpq     = (unsigned short*)alloc((size_t)3 * 512 * CCH * 2);
    unsigned short* wtr     = (unsigned short*)alloc((size_t)4 * 256 * 32 * 2);
    unsigned short* wt_sup0 = (unsigned short*)alloc((size_t)256 * 320 * 2);
    unsigned short* wt_sup  = (unsigned short*)alloc((size_t)3 * 256 * 512 * 2);
    unsigned short* wt_fuse = (unsigned short*)alloc((size_t)1024 * 1024 * 2);
    unsigned short* wt_fsup = (unsigned short*)alloc((size_t)1024 * 1024 * 2);
    unsigned short* fsmeanb = (unsigned short*)alloc((size_t)NBOX * FD * 2);
    float* sew        = (float*)alloc((size_t)N_EDGES * 4);
    int* cnt          = (int*)alloc((size_t)(N_NODES + 1) * 4);
    int* rowptr       = (int*)alloc((size_t)(N_NODES + 1) * 4);
    int* ofs          = (int*)alloc((size_t)(N_NODES + 1) * 4);
    int* ssrc         = (int*)alloc((size_t)N_EDGES * 4);
    int* seid         = (int*)alloc((size_t)N_EDGES * 4);
    int* bcnt         = (int*)alloc(129 * 4);
    int* bptr         = (int*)alloc(129 * 4);
    int* bofs         = (int*)alloc(129 * 4);
    int* snode        = (int*)alloc((size_t)N_NODES * 4);

    const int* srcp = edges;
    const int* dstp = edges + N_EDGES;

    // ---- input bf16 conversion ----
    f32_to_bf16<<<(N_NODES * CIN / 4 + 255) / 256, 256, 0, stream>>>(x, xb, N_NODES * CIN / 4);
    f32_to_bf16<<<(N_EDGES * A_DIM / 4 + 255) / 256, 256, 0, stream>>>(ea, eab, N_EDGES * A_DIM / 4);

    // ---- weight prep ----
    wpq_prep<<<(512 * CIN + 255) / 256, 256, 0, stream>>>(W_msg0, wpq0, CIN);
    wpq_prep3_tiled<<<dim3(128, 3), 256, 0, stream>>>(W_msg, wpq);
    wtr_prep<<<dim3((32 * 256 + 255) / 256, 4), 256, 0, stream>>>(W_msg0, W_msg, wtr);
    transpose_tiled<<<dim3(80, 1),   256, 0, stream>>>(W_sup0, wt_sup0, 320, 256, 0, 0);
    transpose_tiled<<<dim3(128, 3),  256, 0, stream>>>(W_sup,  wt_sup,  512, 256,
                                                       512 * 256, 256 * 512);
    transpose_tiled<<<dim3(1024, 1), 256, 0, stream>>>(W_fuse, wt_fuse, 1024, 1024, 0, 0);
    transpose_tiled<<<dim3(1024, 1), 256, 0, stream>>>(W_fsup, wt_fsup, 1024, 1024, 0, 0);

    // ---- CSR build (edges by dst; nodes by box) ----
    zero_int<<<(N_NODES + 256) / 256, 256, 0, stream>>>(cnt, N_NODES + 1);
    zero_int<<<1, 256, 0, stream>>>(bcnt, 129);
    hist_kernel<<<(N_EDGES + 255) / 256, 256, 0, stream>>>(dstp, N_EDGES, cnt);
    hist_kernel<<<(N_NODES + 255) / 256, 256, 0, stream>>>(bbox, N_NODES, bcnt);
    scan_kernel<<<1, 1024, 0, stream>>>(cnt, rowptr, ofs, N_NODES);
    scan_kernel<<<1, 1024, 0, stream>>>(bcnt, bptr, bofs, NBOX);
    scatter_edges<<<(N_EDGES + 255) / 256, 256, 0, stream>>>(srcp, dstp, ew, ofs, ssrc, sew, seid);
    scatter_box<<<(N_NODES + 255) / 256, 256, 0, stream>>>(bbox, bofs, snode);

    const int GRB = (N_NODES + 127) / 128;   // 157
    const int GEB = (N_EDGES + 127) / 128;   // 782

    // ---- merged R GEMM for all 4 layers: [E,32] @ [32,1024] -> dense Rb4 ----
    mfma_dense<<<GEB * 8, 256, 0, stream>>>(eab, A_DIM, 0, A_DIM, seid,
        nullptr, 0, 0, wtr, nullptr, 0,
        nullptr, 0, 0, Rb4, 0, 0, 2, N_EDGES, A_DIM, 8);

    const long RLS = (long)N_EDGES * 256;   // R layer stride (shorts)

    // ---- head block ----
    mfma_dense<<<GRB * 4, 256, 0, stream>>>(xb, CIN, 0, CIN, nullptr,
        nullptr, 0, 0, wpq0, nullptr, 0,
        nullptr, 0, 0, pq, 512, 0, 0, N_NODES, CIN, 4);
    agg_kernel<<<(N_NODES + 3) / 4, 256, 0, stream>>>(pq, rowptr, ssrc, sew,
        Rb4, out, b_msg0, out, HID, -1, nfbf, 0);
    mfma_dense<<<GRB * 2, 256, 0, stream>>>(nfbf, FD, 0, CCH, nullptr,
        xb, CIN, 0, wt_sup0, b_sup0, 1,
        nullptr, 0, 0, fsbf, FD, 0, 0, N_NODES, CCH + CIN, 2);

    // ---- ResBlocks ----
    for (int i = 0; i < 3; ++i) {
        const int fi = HID + CCH * i, fo = HID + CCH * (i + 1);
        mfma_dense<<<GRB * 4, 256, 0, stream>>>(nfbf, FD, CCH * i, CCH, nullptr,
            nullptr, 0, 0, wpq + (long)i * 512 * CCH, nullptr, 0,
            nullptr, 0, 0, pq, 512, 0, 0, N_NODES, CCH, 4);
        agg_kernel<<<(N_NODES + 3) / 4, 256, 0, stream>>>(pq, rowptr, ssrc, sew,
            Rb4 + (long)(i + 1) * RLS, out, b_msg + i * CCH,
            out, fo, fi, nfbf, CCH * (i + 1));
        mfma_dense<<<GRB * 2, 256, 0, stream>>>(nfbf, FD, CCH * (i + 1), CCH, nullptr,
            fsbf, FD, CCH * i, wt_sup + (long)i * 256 * 512, b_sup + i * CCH, 1,
            nullptr, 0, 0, fsbf, FD, CCH * (i + 1), 0, N_NODES, 2 * CCH, 2);
    }

    // ---- fusion ----
    mfma_dense<<<GRB * 8, 256, 0, stream>>>(nfbf, FD, 0, FD, nullptr,
        nullptr, 0, 0, wt_fuse, b_fuse, 1,
        out, OUT_STRIDE, 0, nullptr, 0, 0, 0, N_NODES, FD, 8);

    // ---- super path ----
    box_mean_csr<<<NBOX * 4, 256, 0, stream>>>(fsbf, bptr, snode, out_super, fsmeanb);
    mfma_dense<<<8, 256, 0, stream>>>(fsmeanb, FD, 0, FD, nullptr,
        nullptr, 0, 0, wt_fsup, b_fsup, 1,
        out_super, OUT_STRIDE, 0, nullptr, 0, 0, 0, NBOX, FD, 8);
}

// Round 6
// 858.397 us; speedup vs baseline: 1.1607x; 1.1607x over previous
//
#include <hip/hip_runtime.h>

#define N_NODES 20000
#define N_EDGES 100000
#define CIN     64
#define A_DIM   32
#define CCH     256
#define NBOX    128
#define FD      1024
#define HID     1024
#define OUT_STRIDE 2048

typedef __attribute__((ext_vector_type(8))) short          short8;
typedef __attribute__((ext_vector_type(8))) unsigned short ushort8;
typedef __attribute__((ext_vector_type(4))) unsigned short ushort4v;
typedef __attribute__((ext_vector_type(4))) float          floatx4;

__device__ __forceinline__ unsigned short f2bf(float f) {
    unsigned int u = __float_as_uint(f);
    u += 0x7fff + ((u >> 16) & 1);
    return (unsigned short)(u >> 16);
}
__device__ __forceinline__ float bf2f(unsigned short h) {
    return __uint_as_float(((unsigned int)h) << 16);
}

// async global->LDS, 16B per lane; LDS dest is wave-uniform base + lane*16
__device__ __forceinline__ void glds16(const unsigned short* g, unsigned short* l) {
    __builtin_amdgcn_global_load_lds(
        (const __attribute__((address_space(1))) unsigned int*)g,
        (__attribute__((address_space(3))) unsigned int*)l,
        16, 0, 0);
}

// ---------------------------------------------------------------------------
// Dense MFMA GEMM, 128x128 tile, BK=32, m97-style single-buffer staging
// (measured-good round-4 structure). A = [seg0 (C0 cols) | seg1] rows, both
// bf16; optional row remap on seg0 via ridx0. B = bf16 Wt[n][k].
// Epilogue: fp32 out -> direct (full-line 4B stores); bf16 out -> LDS-staged
// coalesced path (2 passes of 64 rows through the freed As/Bs LDS, then
// ushort8 stores whose per-instruction footprint is full 64B line segments)
// -- removes the 2x HBM write amplification of scattered 2B stores.
// rmode==2: dense 4-layer R layout idx = (gc>>8)*E*256 + row*256 + (gc&255).
// XCD-aware bijective blockIdx swizzle for row-panel L2 locality.
// ---------------------------------------------------------------------------
__global__ __launch_bounds__(256) void mfma_dense(
    const unsigned short* __restrict__ src0b, int s0, int o0, int C0,
    const int* __restrict__ ridx0,
    const unsigned short* __restrict__ src1b, int s1, int o1,
    const unsigned short* __restrict__ Wt, const float* __restrict__ bias,
    int do_relu,
    float* __restrict__ outf, int sof, int oof,
    unsigned short* __restrict__ outb, int sob, int oob, int rmode,
    int M, int K, int nbc)
{
    __shared__ __align__(16) unsigned short SM[2][4096];   // As=SM[0], Bs=SM[1]

    const int tid  = threadIdx.x;

    // bijective XCD swizzle (works for any gridDim)
    const int nwg  = gridDim.x;
    const int q8   = nwg >> 3, r8 = nwg & 7;
    const int xcd  = blockIdx.x & 7, boff = blockIdx.x >> 3;
    const int bid  = (xcd < r8 ? xcd * (q8 + 1)
                               : r8 * (q8 + 1) + (xcd - r8) * q8) + boff;

    const int rb   = bid / nbc, cb = bid % nbc;
    const int r0   = rb * 128, c0 = cb * 128;
    const int wave = tid >> 6, lane = tid & 63;
    const int quad = lane >> 4, l16 = lane & 15;
    const int wm   = (wave & 1) * 64, wn = (wave >> 1) * 64;

    // staging slot geometry: slot g = i*256 + tid covers LDS bytes [g*16, g*16+16)
    // row = g>>2 (64B rows), k-chunk = (g&3)*8 bf16
    int arow[2], grow[2], brow[2], kch[2];
    #pragma unroll
    for (int i = 0; i < 2; ++i) {
        const int g  = i * 256 + tid;
        const int rr = g >> 2;
        kch[i] = (g & 3) << 3;
        int gr2 = r0 + rr;
        if (gr2 >= M) gr2 = M - 1;
        grow[i] = gr2;
        arow[i] = ridx0 ? ridx0[gr2] : gr2;
        brow[i] = c0 + rr;
    }
    unsigned short* AsW = &SM[0][wave * 512];   // +i*2048 shorts per inst
    unsigned short* BsW = &SM[1][wave * 512];

    floatx4 acc[4][4];
    #pragma unroll
    for (int i = 0; i < 4; ++i)
        #pragma unroll
        for (int j = 0; j < 4; ++j) acc[i][j] = (floatx4){0.f, 0.f, 0.f, 0.f};

    for (int k0 = 0; k0 < K; k0 += 32) {
        #pragma unroll
        for (int i = 0; i < 2; ++i) {
            const int kk = k0 + kch[i];
            const unsigned short* ga = (kk < C0)
                ? src0b + (long)arow[i] * s0 + o0 + kk
                : src1b + (long)grow[i] * s1 + o1 + (kk - C0);
            glds16(ga, AsW + i * 2048);
            glds16(Wt + (long)brow[i] * K + k0 + kch[i], BsW + i * 2048);
        }
        __syncthreads();

        short8 af[4], bfr[4];
        #pragma unroll
        for (int mt = 0; mt < 4; ++mt)
            af[mt] = *(const short8*)(&SM[0][(wm + mt * 16 + l16) * 32 + quad * 8]);
        #pragma unroll
        for (int nt = 0; nt < 4; ++nt)
            bfr[nt] = *(const short8*)(&SM[1][(wn + nt * 16 + l16) * 32 + quad * 8]);
        #pragma unroll
        for (int mt = 0; mt < 4; ++mt)
            #pragma unroll
            for (int nt = 0; nt < 4; ++nt)
                acc[mt][nt] = __builtin_amdgcn_mfma_f32_16x16x32_bf16(
                    af[mt], bfr[nt], acc[mt][nt], 0, 0, 0);
        __syncthreads();
    }

    if (outf) {
        // fp32 path: direct stores (16 lanes x 4B = full 64B line per row/instr)
        #pragma unroll
        for (int nt = 0; nt < 4; ++nt) {
            const int gc = c0 + wn + nt * 16 + l16;
            const float bv = bias ? bias[gc] : 0.f;
            #pragma unroll
            for (int mt = 0; mt < 4; ++mt) {
                #pragma unroll
                for (int reg = 0; reg < 4; ++reg) {
                    const int grr = r0 + wm + mt * 16 + quad * 4 + reg;
                    if (grr < M) {
                        float v = acc[mt][nt][reg] + bv;
                        if (do_relu) v = fmaxf(v, 0.f);
                        outf[(long)grr * sof + oof + gc] = v;
                    }
                }
            }
        }
    }
    if (outb) {
        // bf16 path: LDS-staged coalesced epilogue, 2 passes of 64 rows.
        unsigned short* Cs = &SM[0][0];        // 64*128 shorts = 16KB = As+Bs
        #pragma unroll
        for (int p = 0; p < 2; ++p) {
            if (wm == p * 64) {
                #pragma unroll
                for (int nt = 0; nt < 4; ++nt) {
                    const int col = wn + nt * 16 + l16;
                    const float bv = bias ? bias[c0 + col] : 0.f;
                    #pragma unroll
                    for (int mt = 0; mt < 4; ++mt) {
                        #pragma unroll
                        for (int reg = 0; reg < 4; ++reg) {
                            float v = acc[mt][nt][reg] + bv;
                            if (do_relu) v = fmaxf(v, 0.f);
                            Cs[(mt * 16 + quad * 4 + reg) * 128 + col] = f2bf(v);
                        }
                    }
                }
            }
            __syncthreads();
            const int rl  = tid >> 2;              // 0..63 local row
            const int cc0 = (tid & 3) << 3;        // 4 lanes x 8 shorts = 64B/row/instr
            const int grr2 = r0 + p * 64 + rl;
            if (grr2 < M) {
                const long rowbase = (rmode == 2)
                    ? ((long)(c0 >> 8) * ((long)N_EDGES * 256)
                       + (long)grr2 * 256 + (c0 & 255))
                    : ((long)grr2 * sob + oob + c0);
                #pragma unroll
                for (int j = 0; j < 4; ++j)
                    *(ushort8*)(outb + rowbase + cc0 + j * 32) =
                        *(const ushort8*)(&Cs[rl * 128 + cc0 + j * 32]);
            }
            __syncthreads();
        }
    }
}

// ---------------------------------------------------------------------------
// fp32 -> bf16 bulk convert (n multiple of 4)
// ---------------------------------------------------------------------------
__global__ void f32_to_bf16(const float* __restrict__ in,
                            unsigned short* __restrict__ out, int n4) {
    int i = blockIdx.x * blockDim.x + threadIdx.x;
    if (i < n4) {
        float4 v = ((const float4*)in)[i];
        ushort4v h = (ushort4v){f2bf(v.x), f2bf(v.y), f2bf(v.z), f2bf(v.w)};
        ((ushort4v*)out)[i] = h;
    }
}

// ---------------------------------------------------------------------------
// Aggregation: one wave per dst node. f_out[d] = sum_e relu(P[d]+Q[src]+R[e]+b)
// * ew[e]  (+ residual). Edges CSR-sorted by dst -> no atomics. One-deep
// software prefetch; R read is DENSE sequential (Rb[s*256+c]).
// Writes fp32 into out (final feats_cat) AND bf16 into nfbf (GEMM A input).
// ---------------------------------------------------------------------------
__global__ __launch_bounds__(256) void agg_kernel(
    const unsigned short* __restrict__ pq,   // [N,512] bf16: [P | Q]
    const int* __restrict__ rowptr,
    const int* __restrict__ ssrc,
    const float* __restrict__ sew,
    const unsigned short* __restrict__ Rb,   // dense [E,256] bf16 (this layer)
    const float* __restrict__ resid,         // residual source (out) if rofs>=0
    const float* __restrict__ bias,
    float* __restrict__ out, int fofs, int rofs,
    unsigned short* __restrict__ nfbf, int nofs)
{
    const int wid  = (blockIdx.x * blockDim.x + threadIdx.x) >> 6;
    const int lane = threadIdx.x & 63;
    if (wid >= N_NODES) return;
    const int c = lane * 4;

    const ushort4v p4 = *(const ushort4v*)(pq + (long)wid * 512 + c);
    const float4 bb = *(const float4*)(bias + c);
    float pb[4] = {bf2f(p4[0]) + bb.x, bf2f(p4[1]) + bb.y,
                   bf2f(p4[2]) + bb.z, bf2f(p4[3]) + bb.w};
    float acc[4] = {0.f, 0.f, 0.f, 0.f};

    int s = rowptr[wid];
    const int sEnd = rowptr[wid + 1];

    ushort4v q4n, r4n;
    float wn_ = 0.f;
    if (s < sEnd) {
        const int srcn = ssrc[s];
        wn_ = sew[s];
        q4n = *(const ushort4v*)(pq + (long)srcn * 512 + 256 + c);
        r4n = *(const ushort4v*)(Rb + (long)s * 256 + c);
    }
    while (s < sEnd) {
        const ushort4v q4 = q4n, r4 = r4n;
        const float wgt = wn_;
        ++s;
        if (s < sEnd) {
            const int srcn = ssrc[s];
            wn_ = sew[s];
            q4n = *(const ushort4v*)(pq + (long)srcn * 512 + 256 + c);
            r4n = *(const ushort4v*)(Rb + (long)s * 256 + c);
        }
        #pragma unroll
        for (int j = 0; j < 4; ++j)
            acc[j] += fmaxf(pb[j] + bf2f(q4[j]) + bf2f(r4[j]), 0.f) * wgt;
    }
    if (rofs >= 0) {
        const float4 f4 = *(const float4*)(resid + (long)wid * OUT_STRIDE + rofs + c);
        acc[0] += f4.x; acc[1] += f4.y; acc[2] += f4.z; acc[3] += f4.w;
    }
    float4 o; o.x = acc[0]; o.y = acc[1]; o.z = acc[2]; o.w = acc[3];
    *(float4*)(out + (long)wid * OUT_STRIDE + fofs + c) = o;
    ushort4v hb = (ushort4v){f2bf(acc[0]), f2bf(acc[1]), f2bf(acc[2]), f2bf(acc[3])};
    *(ushort4v*)(nfbf + (long)wid * FD + nofs + c) = hb;
}

// ---------------------------------------------------------------------------
// Weight prep
// ---------------------------------------------------------------------------
// Wpq[n][k]: n<256 -> W0-W1 column n; n>=256 -> W1 column n-256.  W is [2F+32,256].
__global__ void wpq_prep(const float* __restrict__ W, unsigned short* __restrict__ Wpq, int F) {
    int i = blockIdx.x * blockDim.x + threadIdx.x;
    if (i < 512 * F) {
        int nn = i / F, k = i % F;
        float v = (nn < 256) ? (W[k * 256 + nn] - W[(F + k) * 256 + nn])
                             : W[(F + k) * 256 + (nn - 256)];
        Wpq[(long)nn * F + k] = f2bf(v);
    }
}

// Tiled (LDS, coalesced both sides) version of wpq_prep for the 3 ResBlocks.
// Output [512][256] per slab; grid.x = 16*8 = 128, grid.y = slab.
__global__ __launch_bounds__(256) void wpq_prep3_tiled(
    const float* __restrict__ W, unsigned short* __restrict__ Wpq)
{
    __shared__ float tile[32][33];
    const float* Wi = W + (long)blockIdx.y * 544 * 256;
    unsigned short* Wo = Wpq + (long)blockIdx.y * 512 * 256;
    const int nbx = 16;                       // 512/32 n-tiles
    const int n0 = (blockIdx.x % nbx) << 5;
    const int k0 = (blockIdx.x / nbx) << 5;
    const int tx = threadIdx.x & 31, ty = threadIdx.x >> 5;
    #pragma unroll
    for (int r = 0; r < 4; ++r) {
        const int k = k0 + ty + r * 8;
        float v;
        if (n0 < 256)
            v = Wi[(long)k * 256 + n0 + tx] - Wi[(long)(256 + k) * 256 + n0 + tx];
        else
            v = Wi[(long)(256 + k) * 256 + (n0 - 256) + tx];
        tile[ty + r * 8][tx] = v;
    }
    __syncthreads();
    #pragma unroll
    for (int r = 0; r < 4; ++r)
        Wo[(long)(n0 + ty + r * 8) * 256 + k0 + tx] = f2bf(tile[tx][ty + r * 8]);
}

// Generic LDS-tiled transpose+convert: out[n][k] = bf16(in[k][n]).
// K,N multiples of 32; grid.x = (K/32)*(N/32), grid.y = batch.
__global__ __launch_bounds__(256) void transpose_tiled(
    const float* __restrict__ in, unsigned short* __restrict__ out,
    int K, int N, long istride, long ostride)
{
    __shared__ float tile[32][33];
    const float* inp = in + (long)blockIdx.y * istride;
    unsigned short* outp = out + (long)blockIdx.y * ostride;
    const int nbx = N >> 5;
    const int n0 = (blockIdx.x % nbx) << 5;
    const int k0 = (blockIdx.x / nbx) << 5;
    const int tx = threadIdx.x & 31, ty = threadIdx.x >> 5;
    #pragma unroll
    for (int r = 0; r < 4; ++r)
        tile[ty + r * 8][tx] = inp[(long)(k0 + ty + r * 8) * N + n0 + tx];
    __syncthreads();
    #pragma unroll
    for (int r = 0; r < 4; ++r)
        outp[(long)(n0 + ty + r * 8) * K + k0 + tx] = f2bf(tile[tx][ty + r * 8]);
}

// 4 edge-weight transposes (32x256 -> 256x32) in one launch; blockIdx.y=0 is
// the head slice (from W_msg0), 1..3 are the ResBlock slices (from W_msg).
// Concatenated output wtr is [1024][32] (layer-major) for the merged R GEMM.
__global__ void wtr_prep(const float* __restrict__ W_msg0,
                         const float* __restrict__ W_msg,
                         unsigned short* __restrict__ wtr) {
    const int j = blockIdx.y;
    const float* Wi = (j == 0) ? (W_msg0 + 2 * CIN * 256)
                               : (W_msg + (long)(j - 1) * 544 * 256 + 2 * CCH * 256);
    unsigned short* Wo = wtr + (long)j * 256 * 32;
    int i = blockIdx.x * blockDim.x + threadIdx.x;
    if (i < 32 * 256) {
        int k = i / 256, n = i % 256;
        Wo[(long)n * 32 + k] = f2bf(Wi[i]);
    }
}

// ---------------------------------------------------------------------------
// CSR build
// ---------------------------------------------------------------------------
__global__ void zero_int(int* p, int n) {
    int i = blockIdx.x * blockDim.x + threadIdx.x;
    if (i < n) p[i] = 0;
}
__global__ void hist_kernel(const int* __restrict__ keys, int n, int* __restrict__ cnt) {
    int i = blockIdx.x * blockDim.x + threadIdx.x;
    if (i < n) atomicAdd(&cnt[keys[i]], 1);
}
__global__ __launch_bounds__(1024) void scan_kernel(const int* __restrict__ cnt,
                                                    int* __restrict__ rowptr,
                                                    int* __restrict__ ofs, int n) {
    __shared__ int part[1024];
    const int tid = threadIdx.x;
    const int chunk = (n + 1023) >> 10;
    int s = 0;
    for (int j = 0; j < chunk; ++j) {
        int i = tid * chunk + j;
        if (i < n) s += cnt[i];
    }
    part[tid] = s; __syncthreads();
    for (int d = 1; d < 1024; d <<= 1) {
        int v = (tid >= d) ? part[tid - d] : 0;
        __syncthreads();
        part[tid] += v;
        __syncthreads();
    }
    int run = (tid > 0) ? part[tid - 1] : 0;
    for (int j = 0; j < chunk; ++j) {
        int i = tid * chunk + j;
        if (i < n) { rowptr[i] = run; ofs[i] = run; run += cnt[i]; }
    }
    if (tid == 1023) rowptr[n] = part[1023];
}
__global__ void scatter_edges(const int* __restrict__ src, const int* __restrict__ dst,
                              const float* __restrict__ ew, int* __restrict__ ofs,
                              int* __restrict__ ssrc, float* __restrict__ sew,
                              int* __restrict__ seid) {
    int e = blockIdx.x * blockDim.x + threadIdx.x;
    if (e < N_EDGES) {
        int pos = atomicAdd(&ofs[dst[e]], 1);
        ssrc[pos] = src[e];
        sew[pos]  = ew[e];
        seid[pos] = e;
    }
}
__global__ void scatter_box(const int* __restrict__ bbox, int* __restrict__ ofs,
                            int* __restrict__ snode) {
    int i = blockIdx.x * blockDim.x + threadIdx.x;
    if (i < N_NODES) {
        int pos = atomicAdd(&ofs[bbox[i]], 1);
        snode[pos] = i;
    }
}

// ---------------------------------------------------------------------------
// Box mean via CSR (no atomics). Emits fp32 into out_super and bf16 fsmean.
// ---------------------------------------------------------------------------
__global__ __launch_bounds__(256) void box_mean_csr(
    const unsigned short* __restrict__ fsbf, const int* __restrict__ bptr,
    const int* __restrict__ snode, float* __restrict__ out_super,
    unsigned short* __restrict__ fsmeanb)
{
    const int b = blockIdx.x >> 2;
    const int c = ((blockIdx.x & 3) << 8) + threadIdx.x;
    const int s0 = bptr[b], s1 = bptr[b + 1];
    float sum = 0.f;
    for (int s = s0; s < s1; ++s)
        sum += bf2f(fsbf[(long)snode[s] * FD + c]);
    const float mean = sum / fmaxf((float)(s1 - s0), 1.f);
    out_super[(long)b * OUT_STRIDE + HID + c] = mean;
    fsmeanb[(long)b * FD + c] = f2bf(mean);
}

// ---------------------------------------------------------------------------
extern "C" void kernel_launch(void* const* d_in, const int* in_sizes, int n_in,
                              void* d_out, int out_size, void* d_ws, size_t ws_size,
                              hipStream_t stream) {
    const float* x      = (const float*)d_in[0];
    const int*   edges  = (const int*)d_in[1];
    const float* ew     = (const float*)d_in[2];
    const float* ea     = (const float*)d_in[3];
    const int*   bbox   = (const int*)d_in[4];
    const float* W_msg0 = (const float*)d_in[6];
    const float* b_msg0 = (const float*)d_in[7];
    const float* W_sup0 = (const float*)d_in[8];
    const float* b_sup0 = (const float*)d_in[9];
    const float* W_msg  = (const float*)d_in[10];
    const float* b_msg  = (const float*)d_in[11];
    const float* W_sup  = (const float*)d_in[12];
    const float* b_sup  = (const float*)d_in[13];
    const float* W_fuse = (const float*)d_in[14];
    const float* b_fuse = (const float*)d_in[15];
    const float* W_fsup = (const float*)d_in[16];
    const float* b_fsup = (const float*)d_in[17];

    float* out       = (float*)d_out;
    float* out_super = out + (long)N_NODES * OUT_STRIDE;

    // ---- workspace layout ----
    char* w = (char*)d_ws;
    auto alloc = [&](size_t bytes) { char* p = w; w += (bytes + 63) & ~63ULL; return p; };
    unsigned short* fsbf    = (unsigned short*)alloc((size_t)N_NODES * FD * 2);
    unsigned short* nfbf    = (unsigned short*)alloc((size_t)N_NODES * FD * 2);
    unsigned short* pq      = (unsigned short*)alloc((size_t)N_NODES * 512 * 2);
    unsigned short* xb      = (unsigned short*)alloc((size_t)N_NODES * CIN * 2);
    unsigned short* eab     = (unsigned short*)alloc((size_t)N_EDGES * A_DIM * 2);
    unsigned short* Rb4     = (unsigned short*)alloc((size_t)N_EDGES * 1024 * 2);
    unsigned short* wpq0    = (unsigned short*)alloc((size_t)512 * CIN * 2);
    unsigned short* wpq     = (unsigned short*)alloc((size_t)3 * 512 * CCH * 2);
    unsigned short* wtr     = (unsigned short*)alloc((size_t)4 * 256 * 32 * 2);
    unsigned short* wt_sup0 = (unsigned short*)alloc((size_t)256 * 320 * 2);
    unsigned short* wt_sup  = (unsigned short*)alloc((size_t)3 * 256 * 512 * 2);
    unsigned short* wt_fuse = (unsigned short*)alloc((size_t)1024 * 1024 * 2);
    unsigned short* wt_fsup = (unsigned short*)alloc((size_t)1024 * 1024 * 2);
    unsigned short* fsmeanb = (unsigned short*)alloc((size_t)NBOX * FD * 2);
    float* sew        = (float*)alloc((size_t)N_EDGES * 4);
    int* cnt          = (int*)alloc((size_t)(N_NODES + 1) * 4);
    int* rowptr       = (int*)alloc((size_t)(N_NODES + 1) * 4);
    int* ofs          = (int*)alloc((size_t)(N_NODES + 1) * 4);
    int* ssrc         = (int*)alloc((size_t)N_EDGES * 4);
    int* seid         = (int*)alloc((size_t)N_EDGES * 4);
    int* bcnt         = (int*)alloc(129 * 4);
    int* bptr         = (int*)alloc(129 * 4);
    int* bofs         = (int*)alloc(129 * 4);
    int* snode        = (int*)alloc((size_t)N_NODES * 4);

    const int* srcp = edges;
    const int* dstp = edges + N_EDGES;

    // ---- input bf16 conversion ----
    f32_to_bf16<<<(N_NODES * CIN / 4 + 255) / 256, 256, 0, stream>>>(x, xb, N_NODES * CIN / 4);
    f32_to_bf16<<<(N_EDGES * A_DIM / 4 + 255) / 256, 256, 0, stream>>>(ea, eab, N_EDGES * A_DIM / 4);

    // ---- weight prep ----
    wpq_prep<<<(512 * CIN + 255) / 256, 256, 0, stream>>>(W_msg0, wpq0, CIN);
    wpq_prep3_tiled<<<dim3(128, 3), 256, 0, stream>>>(W_msg, wpq);
    wtr_prep<<<dim3((32 * 256 + 255) / 256, 4), 256, 0, stream>>>(W_msg0, W_msg, wtr);
    transpose_tiled<<<dim3(80, 1),   256, 0, stream>>>(W_sup0, wt_sup0, 320, 256, 0, 0);
    transpose_tiled<<<dim3(128, 3),  256, 0, stream>>>(W_sup,  wt_sup,  512, 256,
                                                       512 * 256, 256 * 512);
    transpose_tiled<<<dim3(1024, 1), 256, 0, stream>>>(W_fuse, wt_fuse, 1024, 1024, 0, 0);
    transpose_tiled<<<dim3(1024, 1), 256, 0, stream>>>(W_fsup, wt_fsup, 1024, 1024, 0, 0);

    // ---- CSR build (edges by dst; nodes by box) ----
    zero_int<<<(N_NODES + 256) / 256, 256, 0, stream>>>(cnt, N_NODES + 1);
    zero_int<<<1, 256, 0, stream>>>(bcnt, 129);
    hist_kernel<<<(N_EDGES + 255) / 256, 256, 0, stream>>>(dstp, N_EDGES, cnt);
    hist_kernel<<<(N_NODES + 255) / 256, 256, 0, stream>>>(bbox, N_NODES, bcnt);
    scan_kernel<<<1, 1024, 0, stream>>>(cnt, rowptr, ofs, N_NODES);
    scan_kernel<<<1, 1024, 0, stream>>>(bcnt, bptr, bofs, NBOX);
    scatter_edges<<<(N_EDGES + 255) / 256, 256, 0, stream>>>(srcp, dstp, ew, ofs, ssrc, sew, seid);
    scatter_box<<<(N_NODES + 255) / 256, 256, 0, stream>>>(bbox, bofs, snode);

    const int GRB = (N_NODES + 127) / 128;   // 157
    const int GEB = (N_EDGES + 127) / 128;   // 782

    // ---- merged R GEMM for all 4 layers: [E,32] @ [32,1024] -> dense Rb4 ----
    mfma_dense<<<GEB * 8, 256, 0, stream>>>(eab, A_DIM, 0, A_DIM, seid,
        nullptr, 0, 0, wtr, nullptr, 0,
        nullptr, 0, 0, Rb4, 0, 0, 2, N_EDGES, A_DIM, 8);

    const long RLS = (long)N_EDGES * 256;   // R layer stride (shorts)

    // ---- head block ----
    mfma_dense<<<GRB * 4, 256, 0, stream>>>(xb, CIN, 0, CIN, nullptr,
        nullptr, 0, 0, wpq0, nullptr, 0,
        nullptr, 0, 0, pq, 512, 0, 0, N_NODES, CIN, 4);
    agg_kernel<<<(N_NODES + 3) / 4, 256, 0, stream>>>(pq, rowptr, ssrc, sew,
        Rb4, out, b_msg0, out, HID, -1, nfbf, 0);
    mfma_dense<<<GRB * 2, 256, 0, stream>>>(nfbf, FD, 0, CCH, nullptr,
        xb, CIN, 0, wt_sup0, b_sup0, 1,
        nullptr, 0, 0, fsbf, FD, 0, 0, N_NODES, CCH + CIN, 2);

    // ---- ResBlocks ----
    for (int i = 0; i < 3; ++i) {
        const int fi = HID + CCH * i, fo = HID + CCH * (i + 1);
        mfma_dense<<<GRB * 4, 256, 0, stream>>>(nfbf, FD, CCH * i, CCH, nullptr,
            nullptr, 0, 0, wpq + (long)i * 512 * CCH, nullptr, 0,
            nullptr, 0, 0, pq, 512, 0, 0, N_NODES, CCH, 4);
        agg_kernel<<<(N_NODES + 3) / 4, 256, 0, stream>>>(pq, rowptr, ssrc, sew,
            Rb4 + (long)(i + 1) * RLS, out, b_msg + i * CCH,
            out, fo, fi, nfbf, CCH * (i + 1));
        mfma_dense<<<GRB * 2, 256, 0, stream>>>(nfbf, FD, CCH * (i + 1), CCH, nullptr,
            fsbf, FD, CCH * i, wt_sup + (long)i * 256 * 512, b_sup + i * CCH, 1,
            nullptr, 0, 0, fsbf, FD, CCH * (i + 1), 0, N_NODES, 2 * CCH, 2);
    }

    // ---- fusion ----
    mfma_dense<<<GRB * 8, 256, 0, stream>>>(nfbf, FD, 0, FD, nullptr,
        nullptr, 0, 0, wt_fuse, b_fuse, 1,
        out, OUT_STRIDE, 0, nullptr, 0, 0, 0, N_NODES, FD, 8);

    // ---- super path ----
    box_mean_csr<<<NBOX * 4, 256, 0, stream>>>(fsbf, bptr, snode, out_super, fsmeanb);
    mfma_dense<<<8, 256, 0, stream>>>(fsmeanb, FD, 0, FD, nullptr,
        nullptr, 0, 0, wt_fsup, b_fsup, 1,
        out_super, OUT_STRIDE, 0, nullptr, 0, 0, 0, NBOX, FD, 8);
}

// Round 7
// 789.085 us; speedup vs baseline: 1.2626x; 1.0878x over previous
//
#include <hip/hip_runtime.h>

#define N_NODES 20000
#define N_EDGES 100000
#define CIN     64
#define A_DIM   32
#define CCH     256
#define NBOX    128
#define FD      1024
#define HID     1024
#define OUT_STRIDE 2048

typedef __attribute__((ext_vector_type(8))) short          short8;
typedef __attribute__((ext_vector_type(8))) unsigned short ushort8;
typedef __attribute__((ext_vector_type(4))) unsigned short ushort4v;
typedef __attribute__((ext_vector_type(4))) float          floatx4;

__device__ __forceinline__ unsigned short f2bf(float f) {
    unsigned int u = __float_as_uint(f);
    u += 0x7fff + ((u >> 16) & 1);
    return (unsigned short)(u >> 16);
}
__device__ __forceinline__ float bf2f(unsigned short h) {
    return __uint_as_float(((unsigned int)h) << 16);
}

// async global->LDS, 16B per lane; LDS dest is wave-uniform base + lane*16
__device__ __forceinline__ void glds16(const unsigned short* g, unsigned short* l) {
    __builtin_amdgcn_global_load_lds(
        (const __attribute__((address_space(1))) unsigned int*)g,
        (__attribute__((address_space(3))) unsigned int*)l,
        16, 0, 0);
}

// ---------------------------------------------------------------------------
// GEMM descriptor (dual-dispatch support: one launch can carry two GEMMs).
// ---------------------------------------------------------------------------
struct GD {
    const unsigned short* src0b;
    const unsigned short* src1b;
    const unsigned short* Wt;
    const float* bias;
    const int* ridx0;
    float* outf;
    unsigned short* outb;
    int s0, o0, C0, s1, o1, do_relu, sof, oof, sob, oob, rmode, M, K, nbc;
};

// ---------------------------------------------------------------------------
// Dense MFMA GEMM, 128x128 tile, BK=32, m97-style single-buffer staging.
// Blocks [0,n0) execute descriptor A, the rest descriptor B (block-uniform
// select -> no divergence). Each sub-grid gets its own bijective XCD swizzle.
// bf16 outputs go through the LDS-staged coalesced epilogue (full 64B-line
// stores); rmode==2 is the dense 4-layer R layout.
// ---------------------------------------------------------------------------
__global__ __launch_bounds__(256) void mfma_dense(GD A, GD B, int n0)
{
    __shared__ __align__(16) unsigned short SM[2][4096];   // As=SM[0], Bs=SM[1]

    const int tid = threadIdx.x;
    const bool fa = (int)blockIdx.x < n0;

    const unsigned short* src0b = fa ? A.src0b : B.src0b;
    const unsigned short* src1b = fa ? A.src1b : B.src1b;
    const unsigned short* Wt    = fa ? A.Wt    : B.Wt;
    const float* bias           = fa ? A.bias  : B.bias;
    const int*   ridx0          = fa ? A.ridx0 : B.ridx0;
    float* outf                 = fa ? A.outf  : B.outf;
    unsigned short* outb        = fa ? A.outb  : B.outb;
    const int s0  = fa ? A.s0  : B.s0,  o0  = fa ? A.o0  : B.o0;
    const int C0  = fa ? A.C0  : B.C0;
    const int s1  = fa ? A.s1  : B.s1,  o1  = fa ? A.o1  : B.o1;
    const int do_relu = fa ? A.do_relu : B.do_relu;
    const int sof = fa ? A.sof : B.sof, oof = fa ? A.oof : B.oof;
    const int sob = fa ? A.sob : B.sob, oob = fa ? A.oob : B.oob;
    const int rmode = fa ? A.rmode : B.rmode;
    const int M   = fa ? A.M   : B.M;
    const int K   = fa ? A.K   : B.K;
    const int nbc = fa ? A.nbc : B.nbc;

    // bijective XCD swizzle within this descriptor's sub-grid
    const int nwg = fa ? n0 : (int)gridDim.x - n0;
    const int lb  = (int)blockIdx.x - (fa ? 0 : n0);
    const int q8  = nwg >> 3, r8 = nwg & 7;
    const int xcd = lb & 7, boff = lb >> 3;
    const int bid = (xcd < r8 ? xcd * (q8 + 1)
                              : r8 * (q8 + 1) + (xcd - r8) * q8) + boff;

    const int rb   = bid / nbc, cb = bid % nbc;
    const int r0   = rb * 128, c0 = cb * 128;
    const int wave = tid >> 6, lane = tid & 63;
    const int quad = lane >> 4, l16 = lane & 15;
    const int wm   = (wave & 1) * 64, wn = (wave >> 1) * 64;

    // staging slot geometry: slot g = i*256 + tid covers LDS bytes [g*16, g*16+16)
    // row = g>>2 (64B rows), k-chunk = (g&3)*8 bf16
    int arow[2], grow[2], brow[2], kch[2];
    #pragma unroll
    for (int i = 0; i < 2; ++i) {
        const int g  = i * 256 + tid;
        const int rr = g >> 2;
        kch[i] = (g & 3) << 3;
        int gr2 = r0 + rr;
        if (gr2 >= M) gr2 = M - 1;
        grow[i] = gr2;
        arow[i] = ridx0 ? ridx0[gr2] : gr2;
        brow[i] = c0 + rr;
    }
    unsigned short* AsW = &SM[0][wave * 512];   // +i*2048 shorts per inst
    unsigned short* BsW = &SM[1][wave * 512];

    floatx4 acc[4][4];
    #pragma unroll
    for (int i = 0; i < 4; ++i)
        #pragma unroll
        for (int j = 0; j < 4; ++j) acc[i][j] = (floatx4){0.f, 0.f, 0.f, 0.f};

    for (int k0 = 0; k0 < K; k0 += 32) {
        #pragma unroll
        for (int i = 0; i < 2; ++i) {
            const int kk = k0 + kch[i];
            const unsigned short* ga = (kk < C0)
                ? src0b + (long)arow[i] * s0 + o0 + kk
                : src1b + (long)grow[i] * s1 + o1 + (kk - C0);
            glds16(ga, AsW + i * 2048);
            glds16(Wt + (long)brow[i] * K + k0 + kch[i], BsW + i * 2048);
        }
        __syncthreads();

        short8 af[4], bfr[4];
        #pragma unroll
        for (int mt = 0; mt < 4; ++mt)
            af[mt] = *(const short8*)(&SM[0][(wm + mt * 16 + l16) * 32 + quad * 8]);
        #pragma unroll
        for (int nt = 0; nt < 4; ++nt)
            bfr[nt] = *(const short8*)(&SM[1][(wn + nt * 16 + l16) * 32 + quad * 8]);
        #pragma unroll
        for (int mt = 0; mt < 4; ++mt)
            #pragma unroll
            for (int nt = 0; nt < 4; ++nt)
                acc[mt][nt] = __builtin_amdgcn_mfma_f32_16x16x32_bf16(
                    af[mt], bfr[nt], acc[mt][nt], 0, 0, 0);
        __syncthreads();
    }

    if (outf) {
        #pragma unroll
        for (int nt = 0; nt < 4; ++nt) {
            const int gc = c0 + wn + nt * 16 + l16;
            const float bv = bias ? bias[gc] : 0.f;
            #pragma unroll
            for (int mt = 0; mt < 4; ++mt) {
                #pragma unroll
                for (int reg = 0; reg < 4; ++reg) {
                    const int grr = r0 + wm + mt * 16 + quad * 4 + reg;
                    if (grr < M) {
                        float v = acc[mt][nt][reg] + bv;
                        if (do_relu) v = fmaxf(v, 0.f);
                        outf[(long)grr * sof + oof + gc] = v;
                    }
                }
            }
        }
    }
    if (outb) {
        // bf16 path: LDS-staged coalesced epilogue, 2 passes of 64 rows.
        unsigned short* Cs = &SM[0][0];
        #pragma unroll
        for (int p = 0; p < 2; ++p) {
            if (wm == p * 64) {
                #pragma unroll
                for (int nt = 0; nt < 4; ++nt) {
                    const int col = wn + nt * 16 + l16;
                    const float bv = bias ? bias[c0 + col] : 0.f;
                    #pragma unroll
                    for (int mt = 0; mt < 4; ++mt) {
                        #pragma unroll
                        for (int reg = 0; reg < 4; ++reg) {
                            float v = acc[mt][nt][reg] + bv;
                            if (do_relu) v = fmaxf(v, 0.f);
                            Cs[(mt * 16 + quad * 4 + reg) * 128 + col] = f2bf(v);
                        }
                    }
                }
            }
            __syncthreads();
            const int rl  = tid >> 2;
            const int cc0 = (tid & 3) << 3;
            const int grr2 = r0 + p * 64 + rl;
            if (grr2 < M) {
                const long rowbase = (rmode == 2)
                    ? ((long)(c0 >> 8) * ((long)N_EDGES * 256)
                       + (long)grr2 * 256 + (c0 & 255))
                    : ((long)grr2 * sob + oob + c0);
                #pragma unroll
                for (int j = 0; j < 4; ++j)
                    *(ushort8*)(outb + rowbase + cc0 + j * 32) =
                        *(const ushort8*)(&Cs[rl * 128 + cc0 + j * 32]);
            }
            __syncthreads();
        }
    }
}

// ---------------------------------------------------------------------------
// Aggregation: one wave per dst node, 1-deep software prefetch, dense R.
// ---------------------------------------------------------------------------
__global__ __launch_bounds__(256) void agg_kernel(
    const unsigned short* __restrict__ pq,
    const int* __restrict__ rowptr,
    const int* __restrict__ ssrc,
    const float* __restrict__ sew,
    const unsigned short* __restrict__ Rb,
    const float* __restrict__ resid,
    const float* __restrict__ bias,
    float* __restrict__ out, int fofs, int rofs,
    unsigned short* __restrict__ nfbf, int nofs)
{
    const int wid  = (blockIdx.x * blockDim.x + threadIdx.x) >> 6;
    const int lane = threadIdx.x & 63;
    if (wid >= N_NODES) return;
    const int c = lane * 4;

    const ushort4v p4 = *(const ushort4v*)(pq + (long)wid * 512 + c);
    const float4 bb = *(const float4*)(bias + c);
    float pb[4] = {bf2f(p4[0]) + bb.x, bf2f(p4[1]) + bb.y,
                   bf2f(p4[2]) + bb.z, bf2f(p4[3]) + bb.w};
    float acc[4] = {0.f, 0.f, 0.f, 0.f};

    int s = rowptr[wid];
    const int sEnd = rowptr[wid + 1];

    ushort4v q4n, r4n;
    float wn_ = 0.f;
    if (s < sEnd) {
        const int srcn = ssrc[s];
        wn_ = sew[s];
        q4n = *(const ushort4v*)(pq + (long)srcn * 512 + 256 + c);
        r4n = *(const ushort4v*)(Rb + (long)s * 256 + c);
    }
    while (s < sEnd) {
        const ushort4v q4 = q4n, r4 = r4n;
        const float wgt = wn_;
        ++s;
        if (s < sEnd) {
            const int srcn = ssrc[s];
            wn_ = sew[s];
            q4n = *(const ushort4v*)(pq + (long)srcn * 512 + 256 + c);
            r4n = *(const ushort4v*)(Rb + (long)s * 256 + c);
        }
        #pragma unroll
        for (int j = 0; j < 4; ++j)
            acc[j] += fmaxf(pb[j] + bf2f(q4[j]) + bf2f(r4[j]), 0.f) * wgt;
    }
    if (rofs >= 0) {
        const float4 f4 = *(const float4*)(resid + (long)wid * OUT_STRIDE + rofs + c);
        acc[0] += f4.x; acc[1] += f4.y; acc[2] += f4.z; acc[3] += f4.w;
    }
    float4 o; o.x = acc[0]; o.y = acc[1]; o.z = acc[2]; o.w = acc[3];
    *(float4*)(out + (long)wid * OUT_STRIDE + fofs + c) = o;
    ushort4v hb = (ushort4v){f2bf(acc[0]), f2bf(acc[1]), f2bf(acc[2]), f2bf(acc[3])};
    *(ushort4v*)(nfbf + (long)wid * FD + nofs + c) = hb;
}

// ---------------------------------------------------------------------------
// Mega prep kernel: both f32->bf16 converts + all weight preps in ONE launch.
// Flat region decode on blockIdx.x; all regions 256-thread blocks.
// ---------------------------------------------------------------------------
__device__ __forceinline__ void tr_block(const float* inp, unsigned short* outp,
                                         int K, int N, int bidx, int tid,
                                         float (*tile)[33])
{
    const int nbx = N >> 5;
    const int n0 = (bidx % nbx) << 5;
    const int k0 = (bidx / nbx) << 5;
    const int tx = tid & 31, ty = tid >> 5;
    #pragma unroll
    for (int r = 0; r < 4; ++r)
        tile[ty + r * 8][tx] = inp[(long)(k0 + ty + r * 8) * N + n0 + tx];
    __syncthreads();
    #pragma unroll
    for (int r = 0; r < 4; ++r)
        outp[(long)(n0 + ty + r * 8) * K + k0 + tx] = f2bf(tile[tx][ty + r * 8]);
}

#define PB_CVTX  1250   // 20000*64/4/256
#define PB_CVTE  3125   // 100000*32/4/256
#define PB_WPQ0  128    // 512*64/256
#define PB_WPQ3  384    // 3*128
#define PB_WTR   128    // 4*32
#define PB_TS0   80     // (320/32)*(256/32)
#define PB_TS3   384    // 3*128
#define PB_TF    1024   // (1024/32)^2
#define PREP_BLOCKS (PB_CVTX+PB_CVTE+PB_WPQ0+PB_WPQ3+PB_WTR+PB_TS0+PB_TS3+PB_TF+PB_TF)

__global__ __launch_bounds__(256) void prep_all(
    const float* __restrict__ x, const float* __restrict__ ea,
    const float* __restrict__ W_msg0, const float* __restrict__ W_msg,
    const float* __restrict__ W_sup0, const float* __restrict__ W_sup,
    const float* __restrict__ W_fuse, const float* __restrict__ W_fsup,
    unsigned short* __restrict__ xb, unsigned short* __restrict__ eab,
    unsigned short* __restrict__ wpq0, unsigned short* __restrict__ wpq,
    unsigned short* __restrict__ wtr,
    unsigned short* __restrict__ wt_sup0, unsigned short* __restrict__ wt_sup,
    unsigned short* __restrict__ wt_fuse, unsigned short* __restrict__ wt_fsup)
{
    __shared__ float tile[32][33];
    const int tid = threadIdx.x;
    int b = blockIdx.x;

    if (b < PB_CVTX) {                       // x -> xb
        int i = b * 256 + tid;
        float4 v = ((const float4*)x)[i];
        ((ushort4v*)xb)[i] = (ushort4v){f2bf(v.x), f2bf(v.y), f2bf(v.z), f2bf(v.w)};
        return;
    }
    b -= PB_CVTX;
    if (b < PB_CVTE) {                       // ea -> eab
        int i = b * 256 + tid;
        float4 v = ((const float4*)ea)[i];
        ((ushort4v*)eab)[i] = (ushort4v){f2bf(v.x), f2bf(v.y), f2bf(v.z), f2bf(v.w)};
        return;
    }
    b -= PB_CVTE;
    if (b < PB_WPQ0) {                       // head wpq (F=64)
        int i = b * 256 + tid;
        int nn = i >> 6, k = i & 63;
        float v = (nn < 256) ? (W_msg0[k * 256 + nn] - W_msg0[(64 + k) * 256 + nn])
                             : (W_msg0[(64 + k) * 256 + (nn - 256)]);
        wpq0[(long)nn * 64 + k] = f2bf(v);
        return;
    }
    b -= PB_WPQ0;
    if (b < PB_WPQ3) {                       // 3 ResBlock wpq slabs, tiled
        const int slab = b / 128, bb = b % 128;
        const float* Wi = W_msg + (long)slab * 544 * 256;
        unsigned short* Wo = wpq + (long)slab * 512 * 256;
        const int n0 = (bb & 15) << 5;       // 16 n-tiles
        const int k0 = (bb >> 4) << 5;       // 8 k-tiles
        const int tx = tid & 31, ty = tid >> 5;
        #pragma unroll
        for (int r = 0; r < 4; ++r) {
            const int k = k0 + ty + r * 8;
            float v;
            if (n0 < 256)
                v = Wi[(long)k * 256 + n0 + tx] - Wi[(long)(256 + k) * 256 + n0 + tx];
            else
                v = Wi[(long)(256 + k) * 256 + (n0 - 256) + tx];
            tile[ty + r * 8][tx] = v;
        }
        __syncthreads();
        #pragma unroll
        for (int r = 0; r < 4; ++r)
            Wo[(long)(n0 + ty + r * 8) * 256 + k0 + tx] = f2bf(tile[tx][ty + r * 8]);
        return;
    }
    b -= PB_WPQ3;
    if (b < PB_WTR) {                        // 4 edge-weight slabs [256][32]
        const int j = b >> 5;
        const float* Wi = (j == 0) ? (W_msg0 + 2 * CIN * 256)
                                   : (W_msg + (long)(j - 1) * 544 * 256 + 2 * CCH * 256);
        unsigned short* Wo = wtr + (long)j * 256 * 32;
        int i = (b & 31) * 256 + tid;        // < 8192
        int k = i >> 8, n = i & 255;
        Wo[(long)n * 32 + k] = f2bf(Wi[i]);
        return;
    }
    b -= PB_WTR;
    if (b < PB_TS0) { tr_block(W_sup0, wt_sup0, 320, 256, b, tid, tile); return; }
    b -= PB_TS0;
    if (b < PB_TS3) {
        const int slab = b / 128;
        tr_block(W_sup + (long)slab * 512 * 256, wt_sup + (long)slab * 256 * 512,
                 512, 256, b % 128, tid, tile);
        return;
    }
    b -= PB_TS3;
    if (b < PB_TF) { tr_block(W_fuse, wt_fuse, 1024, 1024, b, tid, tile); return; }
    b -= PB_TF;
    tr_block(W_fsup, wt_fsup, 1024, 1024, b, tid, tile);
}

// ---------------------------------------------------------------------------
// CSR build (edge + box variants merged per stage)
// ---------------------------------------------------------------------------
__global__ void zero2(int* __restrict__ cnt, int* __restrict__ bcnt) {
    int i = blockIdx.x * blockDim.x + threadIdx.x;
    if (i < N_NODES + 1) cnt[i] = 0;
    else if (i - (N_NODES + 1) < 129) bcnt[i - (N_NODES + 1)] = 0;
}
__global__ void hist2(const int* __restrict__ dst, const int* __restrict__ bbox,
                      int* __restrict__ cnt, int* __restrict__ bcnt) {
    int i = blockIdx.x * blockDim.x + threadIdx.x;
    if (i < N_EDGES) atomicAdd(&cnt[dst[i]], 1);
    else if (i - N_EDGES < N_NODES) atomicAdd(&bcnt[bbox[i - N_EDGES]], 1);
}
__global__ __launch_bounds__(1024) void scan2(
    const int* __restrict__ cnt,  int* __restrict__ rowptr, int* __restrict__ ofs,
    const int* __restrict__ bcnt, int* __restrict__ bptr,   int* __restrict__ bofs)
{
    __shared__ int part[1024];
    const int tid = threadIdx.x;
    const int n = blockIdx.x == 0 ? N_NODES : NBOX;
    const int* c   = blockIdx.x == 0 ? cnt    : bcnt;
    int* rp        = blockIdx.x == 0 ? rowptr : bptr;
    int* op        = blockIdx.x == 0 ? ofs    : bofs;
    const int chunk = (n + 1023) >> 10;
    int s = 0;
    for (int j = 0; j < chunk; ++j) {
        int i = tid * chunk + j;
        if (i < n) s += c[i];
    }
    part[tid] = s; __syncthreads();
    for (int d = 1; d < 1024; d <<= 1) {
        int v = (tid >= d) ? part[tid - d] : 0;
        __syncthreads();
        part[tid] += v;
        __syncthreads();
    }
    int run = (tid > 0) ? part[tid - 1] : 0;
    for (int j = 0; j < chunk; ++j) {
        int i = tid * chunk + j;
        if (i < n) { rp[i] = run; op[i] = run; run += c[i]; }
    }
    if (tid == 1023) rp[n] = part[1023];
}
__global__ void scatter2(const int* __restrict__ src, const int* __restrict__ dst,
                         const float* __restrict__ ew, int* __restrict__ ofs,
                         int* __restrict__ ssrc, float* __restrict__ sew,
                         int* __restrict__ seid,
                         const int* __restrict__ bbox, int* __restrict__ bofs,
                         int* __restrict__ snode) {
    int i = blockIdx.x * blockDim.x + threadIdx.x;
    if (i < N_EDGES) {
        int pos = atomicAdd(&ofs[dst[i]], 1);
        ssrc[pos] = src[i];
        sew[pos]  = ew[i];
        seid[pos] = i;
    } else if (i - N_EDGES < N_NODES) {
        int j = i - N_EDGES;
        int pos = atomicAdd(&bofs[bbox[j]], 1);
        snode[pos] = j;
    }
}

// ---------------------------------------------------------------------------
// Box mean via CSR. Emits fp32 into out_super and bf16 fsmean.
// ---------------------------------------------------------------------------
__global__ __launch_bounds__(256) void box_mean_csr(
    const unsigned short* __restrict__ fsbf, const int* __restrict__ bptr,
    const int* __restrict__ snode, float* __restrict__ out_super,
    unsigned short* __restrict__ fsmeanb)
{
    const int b = blockIdx.x >> 2;
    const int c = ((blockIdx.x & 3) << 8) + threadIdx.x;
    const int s0 = bptr[b], s1 = bptr[b + 1];
    float sum = 0.f;
    for (int s = s0; s < s1; ++s)
        sum += bf2f(fsbf[(long)snode[s] * FD + c]);
    const float mean = sum / fmaxf((float)(s1 - s0), 1.f);
    out_super[(long)b * OUT_STRIDE + HID + c] = mean;
    fsmeanb[(long)b * FD + c] = f2bf(mean);
}

// ---------------------------------------------------------------------------
extern "C" void kernel_launch(void* const* d_in, const int* in_sizes, int n_in,
                              void* d_out, int out_size, void* d_ws, size_t ws_size,
                              hipStream_t stream) {
    const float* x      = (const float*)d_in[0];
    const int*   edges  = (const int*)d_in[1];
    const float* ew     = (const float*)d_in[2];
    const float* ea     = (const float*)d_in[3];
    const int*   bbox   = (const int*)d_in[4];
    const float* W_msg0 = (const float*)d_in[6];
    const float* b_msg0 = (const float*)d_in[7];
    const float* W_sup0 = (const float*)d_in[8];
    const float* b_sup0 = (const float*)d_in[9];
    const float* W_msg  = (const float*)d_in[10];
    const float* b_msg  = (const float*)d_in[11];
    const float* W_sup  = (const float*)d_in[12];
    const float* b_sup  = (const float*)d_in[13];
    const float* W_fuse = (const float*)d_in[14];
    const float* b_fuse = (const float*)d_in[15];
    const float* W_fsup = (const float*)d_in[16];
    const float* b_fsup = (const float*)d_in[17];

    float* out       = (float*)d_out;
    float* out_super = out + (long)N_NODES * OUT_STRIDE;

    // ---- workspace layout ----
    char* w = (char*)d_ws;
    auto alloc = [&](size_t bytes) { char* p = w; w += (bytes + 63) & ~63ULL; return p; };
    unsigned short* fsbf    = (unsigned short*)alloc((size_t)N_NODES * FD * 2);
    unsigned short* nfbf    = (unsigned short*)alloc((size_t)N_NODES * FD * 2);
    unsigned short* pq      = (unsigned short*)alloc((size_t)N_NODES * 512 * 2);
    unsigned short* xb      = (unsigned short*)alloc((size_t)N_NODES * CIN * 2);
    unsigned short* eab     = (unsigned short*)alloc((size_t)N_EDGES * A_DIM * 2);
    unsigned short* Rb4     = (unsigned short*)alloc((size_t)N_EDGES * 1024 * 2);
    unsigned short* wpq0    = (unsigned short*)alloc((size_t)512 * CIN * 2);
    unsigned short* wpq     = (unsigned short*)alloc((size_t)3 * 512 * CCH * 2);
    unsigned short* wtr     = (unsigned short*)alloc((size_t)4 * 256 * 32 * 2);
    unsigned short* wt_sup0 = (unsigned short*)alloc((size_t)256 * 320 * 2);
    unsigned short* wt_sup  = (unsigned short*)alloc((size_t)3 * 256 * 512 * 2);
    unsigned short* wt_fuse = (unsigned short*)alloc((size_t)1024 * 1024 * 2);
    unsigned short* wt_fsup = (unsigned short*)alloc((size_t)1024 * 1024 * 2);
    unsigned short* fsmeanb = (unsigned short*)alloc((size_t)NBOX * FD * 2);
    float* sew        = (float*)alloc((size_t)N_EDGES * 4);
    int* cnt          = (int*)alloc((size_t)(N_NODES + 1) * 4);
    int* rowptr       = (int*)alloc((size_t)(N_NODES + 1) * 4);
    int* ofs          = (int*)alloc((size_t)(N_NODES + 1) * 4);
    int* ssrc         = (int*)alloc((size_t)N_EDGES * 4);
    int* seid         = (int*)alloc((size_t)N_EDGES * 4);
    int* bcnt         = (int*)alloc(129 * 4);
    int* bptr         = (int*)alloc(129 * 4);
    int* bofs         = (int*)alloc(129 * 4);
    int* snode        = (int*)alloc((size_t)N_NODES * 4);

    const int* srcp = edges;
    const int* dstp = edges + N_EDGES;

    // ---- prep (1 launch) ----
    prep_all<<<PREP_BLOCKS, 256, 0, stream>>>(
        x, ea, W_msg0, W_msg, W_sup0, W_sup, W_fuse, W_fsup,
        xb, eab, wpq0, wpq, wtr, wt_sup0, wt_sup, wt_fuse, wt_fsup);

    // ---- CSR build (4 launches) ----
    zero2<<<(N_NODES + 130 + 255) / 256, 256, 0, stream>>>(cnt, bcnt);
    hist2<<<(N_EDGES + N_NODES + 255) / 256, 256, 0, stream>>>(dstp, bbox, cnt, bcnt);
    scan2<<<2, 1024, 0, stream>>>(cnt, rowptr, ofs, bcnt, bptr, bofs);
    scatter2<<<(N_EDGES + N_NODES + 255) / 256, 256, 0, stream>>>(
        srcp, dstp, ew, ofs, ssrc, sew, seid, bbox, bofs, snode);

    const int GRB = (N_NODES + 127) / 128;   // 157
    const int GEB = (N_EDGES + 127) / 128;   // 782
    const long RLS = (long)N_EDGES * 256;    // R layer stride (shorts)

    auto mk = [](const unsigned short* src0b, int s0, int o0, int C0,
                 const int* ridx0,
                 const unsigned short* src1b, int s1, int o1,
                 const unsigned short* Wt, const float* bias, int relu,
                 float* outf, int sof, int oof,
                 unsigned short* outb, int sob, int oob, int rmode,
                 int M, int K, int nbc) {
        GD g;
        g.src0b = src0b; g.s0 = s0; g.o0 = o0; g.C0 = C0;
        g.ridx0 = ridx0;
        g.src1b = src1b; g.s1 = s1; g.o1 = o1;
        g.Wt = Wt; g.bias = bias; g.do_relu = relu;
        g.outf = outf; g.sof = sof; g.oof = oof;
        g.outb = outb; g.sob = sob; g.oob = oob; g.rmode = rmode;
        g.M = M; g.K = K; g.nbc = nbc;
        return g;
    };

    GD gR   = mk(eab, A_DIM, 0, A_DIM, seid, nullptr, 0, 0, wtr, nullptr, 0,
                 nullptr, 0, 0, Rb4, 0, 0, 2, N_EDGES, A_DIM, 8);
    GD gPQh = mk(xb, CIN, 0, CIN, nullptr, nullptr, 0, 0, wpq0, nullptr, 0,
                 nullptr, 0, 0, pq, 512, 0, 0, N_NODES, CIN, 4);
    GD gS0  = mk(nfbf, FD, 0, CCH, nullptr, xb, CIN, 0, wt_sup0, b_sup0, 1,
                 nullptr, 0, 0, fsbf, FD, 0, 0, N_NODES, CCH + CIN, 2);
    GD gPQ[3], gS[3];
    for (int i = 0; i < 3; ++i) {
        gPQ[i] = mk(nfbf, FD, CCH * i, CCH, nullptr, nullptr, 0, 0,
                    wpq + (long)i * 512 * CCH, nullptr, 0,
                    nullptr, 0, 0, pq, 512, 0, 0, N_NODES, CCH, 4);
        gS[i]  = mk(nfbf, FD, CCH * (i + 1), CCH, nullptr, fsbf, FD, CCH * i,
                    wt_sup + (long)i * 256 * 512, b_sup + i * CCH, 1,
                    nullptr, 0, 0, fsbf, FD, CCH * (i + 1), 0, N_NODES, 2 * CCH, 2);
    }
    GD gFU  = mk(nfbf, FD, 0, FD, nullptr, nullptr, 0, 0, wt_fuse, b_fuse, 1,
                 out, OUT_STRIDE, 0, nullptr, 0, 0, 0, N_NODES, FD, 8);
    GD gFS  = mk(fsmeanb, FD, 0, FD, nullptr, nullptr, 0, 0, wt_fsup, b_fsup, 1,
                 out_super, OUT_STRIDE, 0, nullptr, 0, 0, 0, NBOX, FD, 8);

    const int AGRID = (N_NODES + 3) / 4;

    // ---- R GEMM (all 4 layers) || head pq GEMM ----
    mfma_dense<<<GEB * 8 + GRB * 4, 256, 0, stream>>>(gR, gPQh, GEB * 8);

    // ---- head agg ----
    agg_kernel<<<AGRID, 256, 0, stream>>>(pq, rowptr, ssrc, sew,
        Rb4, out, b_msg0, out, HID, -1, nfbf, 0);

    // ---- [sup_head || pq_res0] -> agg_res0 -> [sup_res0 || pq_res1] -> ... ----
    mfma_dense<<<GRB * 6, 256, 0, stream>>>(gS0, gPQ[0], GRB * 2);
    for (int i = 0; i < 3; ++i) {
        agg_kernel<<<AGRID, 256, 0, stream>>>(pq, rowptr, ssrc, sew,
            Rb4 + (long)(i + 1) * RLS, out, b_msg + i * CCH,
            out, HID + CCH * (i + 1), HID + CCH * i, nfbf, CCH * (i + 1));
        if (i < 2)
            mfma_dense<<<GRB * 6, 256, 0, stream>>>(gS[i], gPQ[i + 1], GRB * 2);
    }

    // ---- [sup_res2 || fusion] ----
    mfma_dense<<<GRB * 10, 256, 0, stream>>>(gS[2], gFU, GRB * 2);

    // ---- super path ----
    box_mean_csr<<<NBOX * 4, 256, 0, stream>>>(fsbf, bptr, snode, out_super, fsmeanb);
    mfma_dense<<<8, 256, 0, stream>>>(gFS, gFS, 8);
}